// Round 2
// baseline (116.033 us; speedup 1.0000x reference)
//
#include <hip/hip_runtime.h>
#include <hip/hip_bf16.h>
#include <math.h>

#define N_Q   512
#define M_ALL 2048
#define CHN   256
#define TOPK  6
#define NREF  10
#define INV_C (1.0f / 256.0f)

// ws layout (float offsets):
//   [WS_AW_F   ..) aw  : micro_all*(w-1/C) as bf16 [M][C]  (u16 view, 1 MB)
//   [WS_BIAS_F ..) bias: sum_c micro_all*aw          [M] f32 (8 KB)
#define WS_AW_F   4096
#define WS_BIAS_F (WS_AW_F + (M_ALL * CHN) / 2)

typedef __bf16 bf16x8 __attribute__((ext_vector_type(8)));
typedef float  f32x4  __attribute__((ext_vector_type(4)));

static __device__ __forceinline__ unsigned short bfbits(float x) {
    __bf16 h = (__bf16)x;
    unsigned short u;
    __builtin_memcpy(&u, &h, 2);
    return u;
}

// sortable u32 key with 11-bit m-index embedded in the low (dropped) mantissa bits
static __device__ __forceinline__ unsigned key_of(float f, int m) {
    unsigned u = __float_as_uint(f);
    u = (u & 0x80000000u) ? ~u : (u | 0x80000000u);
    return (u & 0xFFFFF800u) | (unsigned)m;
}

// ============ kernel 1: one-time A-side prep ============
// aw[m][c] = micro_all[m][c] * (w[c]-1/C) in bf16; bias[m] = sum_c a*aw (fp32).
// Removes the 8x-replicated fp32->bf16 conversion from the hot kernel.
__global__ __launch_bounds__(256) void gcn_prep(
    const float* __restrict__ micro_all,
    const float* __restrict__ fc_w,
    unsigned short* __restrict__ aw,
    float* __restrict__ bias,
    float* __restrict__ out)
{
    const int t    = threadIdx.x;
    const int wave = t >> 6;
    const int lane = t & 63;
    const int row  = blockIdx.x * 4 + wave;

    if (blockIdx.x == 0 && t == 0) out[N_Q * CHN] = 1e-4f;  // loss seed

    const float4 a = *(const float4*)(micro_all + (size_t)row * CHN + lane * 4);
    float4 w = *(const float4*)(fc_w + lane * 4);
    w.x -= INV_C; w.y -= INV_C; w.z -= INV_C; w.w -= INV_C;

    const float sx = a.x * w.x, sy = a.y * w.y, sz = a.z * w.z, sw = a.w * w.w;
    ushort4 pk;
    pk.x = bfbits(sx); pk.y = bfbits(sy); pk.z = bfbits(sz); pk.w = bfbits(sw);
    *(ushort4*)(aw + (size_t)row * CHN + lane * 4) = pk;

    float p = a.x * sx + a.y * sy + a.z * sz + a.w * sw;
    #pragma unroll
    for (int mask = 32; mask >= 1; mask >>= 1)
        p += __shfl_xor(p, mask, 64);
    if (lane == 0) bias[row] = p;
}

// ============ kernel 2: fused GEMM (logits in LDS) + topk + refine + epilogue ============
// 64 blocks x 1024 threads. Block owns 8 n-rows, all 2048 m.
// B-fragments hoisted to regs once; A-fragments are single dwordx4 loads from aw (L2).
// Logits never touch global memory. One __syncthreads total.
__global__ __launch_bounds__(1024) void gcn_main(
    const unsigned short* __restrict__ aw,
    const float* __restrict__ bias,
    const float* __restrict__ micro,
    const float* __restrict__ label,
    const float* __restrict__ micro_all,
    const float* __restrict__ label_all,
    const float* __restrict__ fc_w,
    float* __restrict__ out)
{
    __shared__ float sL[8][M_ALL + 8];   // 8 x 2056 x 4B = 65.8 KB

    const int t    = threadIdx.x;
    const int w    = t >> 6;          // wave 0..15
    const int lane = t & 63;
    const int l15  = lane & 15;
    const int quad = lane >> 4;       // 0..3
    const int n0   = blockIdx.x * 8;

    // ---- hoist B-fragments: 8 n-rows (rows 8..15 of the MFMA tile are discarded) ----
    bf16x8 bfr[8];
    {
        const float* brow = micro + (size_t)(n0 + (l15 & 7)) * CHN;
        #pragma unroll
        for (int ks = 0; ks < 8; ++ks) {
            const float4 u0 = *(const float4*)(brow + ks * 32 + quad * 8);
            const float4 u1 = *(const float4*)(brow + ks * 32 + quad * 8 + 4);
            bf16x8 b;
            b[0] = (__bf16)u0.x; b[1] = (__bf16)u0.y; b[2] = (__bf16)u0.z; b[3] = (__bf16)u0.w;
            b[4] = (__bf16)u1.x; b[5] = (__bf16)u1.y; b[6] = (__bf16)u1.z; b[7] = (__bf16)u1.w;
            bfr[ks] = b;
        }
    }

    // ---- GEMM: wave w handles m-subtiles s = w, w+16, ..., w+112 (8 of 128) ----
    #pragma unroll 2
    for (int si = 0; si < 8; ++si) {
        const int s    = si * 16 + w;
        const int mrow = s * 16 + l15;
        const unsigned short* arow = aw + (size_t)mrow * CHN;

        f32x4 acc = {0.f, 0.f, 0.f, 0.f};
        #pragma unroll
        for (int ks = 0; ks < 8; ++ks) {
            const bf16x8 afr = *(const bf16x8*)(arow + ks * 32 + quad * 8);
            acc = __builtin_amdgcn_mfma_f32_16x16x32_bf16(bfr[ks], afr, acc, 0, 0, 0);
        }

        const float bs = bias[mrow];
        if (quad < 2) {
            #pragma unroll
            for (int r = 0; r < 4; ++r)
                sL[quad * 4 + r][s * 16 + l15] = bs - 2.f * acc[r];
        }
    }
    __syncthreads();

    // ---- per-wave exact top-10 + refine + softmax + epilogue (waves 0..7, n = n0+w) ----
    if (w < 8) {
        const int n = n0 + w;

        // 32 packed keys per lane: m = j*64 + lane (bank-conflict-free LDS reads)
        unsigned loc[32];
        #pragma unroll
        for (int j = 0; j < 32; ++j)
            loc[j] = key_of(sL[w][j * 64 + lane], j * 64 + lane);

        unsigned cand[NREF];
        #pragma unroll
        for (int k = 0; k < NREF; ++k) {
            unsigned best = loc[0];
            #pragma unroll
            for (int j = 1; j < 32; ++j) best = (loc[j] > best) ? loc[j] : best;
            #pragma unroll
            for (int mask = 32; mask > 0; mask >>= 1) {
                const unsigned ov = __shfl_xor(best, mask, 64);
                best = (ov > best) ? ov : best;
            }
            cand[k] = best;
            #pragma unroll
            for (int j = 0; j < 32; ++j)
                if (loc[j] == best) loc[j] = 0u;
        }

        // exact fp32 recompute of the 10 candidates (values uniform across wave)
        const float4 b4 = *(const float4*)(micro + (size_t)n * CHN + lane * 4);
        float4 w4 = *(const float4*)(fc_w + lane * 4);
        w4.x -= INV_C; w4.y -= INV_C; w4.z -= INV_C; w4.w -= INV_C;

        float ex[NREF];
        #pragma unroll
        for (int c = 0; c < NREF; ++c) {
            const int m = (int)(cand[c] & 0x7FFu);
            const float4 a = *(const float4*)(micro_all + (size_t)m * CHN + lane * 4);
            const float dx = a.x - b4.x;
            const float dy = a.y - b4.y;
            const float dz = a.z - b4.z;
            const float dw = a.w - b4.w;
            float acc = dx * dx * w4.x + dy * dy * w4.y + dz * dz * w4.z + dw * dw * w4.w;
            #pragma unroll
            for (int mask = 32; mask >= 1; mask >>= 1)
                acc += __shfl_xor(acc, mask, 64);
            ex[c] = acc;
        }

        // exact top-6 of 10 (index-tracked, identical in every lane)
        float top_val[TOPK];
        int   top_idx[TOPK];
        unsigned rtk = 0u;
        #pragma unroll
        for (int k = 0; k < TOPK; ++k) {
            float best = -INFINITY;
            int   bi   = 0;
            #pragma unroll
            for (int c = 0; c < NREF; ++c) {
                const bool avail = ((rtk >> c) & 1u) == 0u;
                const float cv = ex[c];
                if (avail && cv > best) { best = cv; bi = c; }
            }
            top_val[k] = best;
            top_idx[k] = (int)(cand[bi] & 0x7FFu);
            rtk |= 1u << bi;
        }

        // softmax over exact top-6
        const float mx = top_val[0];
        float e[TOPK];
        float esum = 0.0f;
        #pragma unroll
        for (int k = 0; k < TOPK; ++k) { e[k] = __expf(top_val[k] - mx); esum += e[k]; }
        const float inv = 1.0f / esum;

        // epilogue: out[n][c] for c = lane*4 .. lane*4+3
        float4 o4 = b4;
        #pragma unroll
        for (int k = 0; k < TOPK; ++k) {
            const float wk = e[k] * inv;
            const float4 a = *(const float4*)(micro_all + (size_t)top_idx[k] * CHN + lane * 4);
            o4.x += wk * a.x; o4.y += wk * a.y; o4.z += wk * a.z; o4.w += wk * a.w;
        }
        *(float4*)(out + (size_t)n * CHN + lane * 4) = o4;

        if (lane == 0) {
            const float lab = label[n];
            float l = 0.0f;
            #pragma unroll
            for (int k = 0; k < TOPK; ++k)
                l += (e[k] * inv) * fabsf(label_all[top_idx[k]] - lab);
            atomicAdd(out + N_Q * CHN, l * (1.0f / (float)N_Q));
        }
    }
}

extern "C" void kernel_launch(void* const* d_in, const int* in_sizes, int n_in,
                              void* d_out, int out_size, void* d_ws, size_t ws_size,
                              hipStream_t stream) {
    const float* micro     = (const float*)d_in[0];
    const float* label     = (const float*)d_in[1];
    const float* micro_all = (const float*)d_in[2];
    const float* label_all = (const float*)d_in[3];
    const float* fc_w      = (const float*)d_in[4];
    float* out  = (float*)d_out;
    float* ws   = (float*)d_ws;
    unsigned short* aw   = (unsigned short*)(ws + WS_AW_F);
    float*          bias = ws + WS_BIAS_F;

    gcn_prep<<<M_ALL / 4, 256, 0, stream>>>(micro_all, fc_w, aw, bias, out);
    gcn_main<<<N_Q / 8, 1024, 0, stream>>>(aw, bias, micro, label, micro_all,
                                           label_all, fc_w, out);
}

// Round 3
// 88.570 us; speedup vs baseline: 1.3101x; 1.3101x over previous
//
#include <hip/hip_runtime.h>
#include <hip/hip_bf16.h>
#include <math.h>

#define N_Q   512
#define M_ALL 2048
#define CHN   256
#define TOPK  6
#define NREF  10
#define INV_C (1.0f / 256.0f)

// ws layout (float offsets):
//   [WS_AW_F   ..) aw   : micro_all*(w-1/C) bf16 [M][C]   (1 MB)
//   [WS_BIAS_F ..) bias : sum_c a*aw f32 [M]               (8 KB)
//   [WS_BMIC_F ..) bmic : micro bf16 [N][C]                (256 KB)
//   [WS_LOGIT_F..) logits f32 [N][M]                       (4 MB)
#define WS_AW_F    4096
#define WS_BIAS_F  (WS_AW_F + (M_ALL * CHN) / 2)
#define WS_BMIC_F  (WS_BIAS_F + M_ALL)
#define WS_LOGIT_F (WS_BMIC_F + (N_Q * CHN) / 2)

typedef __bf16 bf16x8 __attribute__((ext_vector_type(8)));
typedef float  f32x4  __attribute__((ext_vector_type(4)));

static __device__ __forceinline__ unsigned short bfbits(float x) {
    __bf16 h = (__bf16)x;
    unsigned short u;
    __builtin_memcpy(&u, &h, 2);
    return u;
}

// sortable u32 key with 11-bit m-index embedded in the low (dropped) mantissa bits
static __device__ __forceinline__ unsigned key_of(float f, int m) {
    unsigned u = __float_as_uint(f);
    u = (u & 0x80000000u) ? ~u : (u | 0x80000000u);
    return (u & 0xFFFFF800u) | (unsigned)m;
}

// ============ kernel 1: one-time bf16 prep (both operands) + bias ============
// blocks 0..511  : micro_all -> aw (bf16, pre-scaled by w-1/C) + bias
// blocks 512..639: micro     -> bmic (bf16)
__global__ __launch_bounds__(256) void gcn_prep(
    const float* __restrict__ micro_all,
    const float* __restrict__ micro,
    const float* __restrict__ fc_w,
    unsigned short* __restrict__ aw,
    float* __restrict__ bias,
    unsigned short* __restrict__ bmic,
    float* __restrict__ out)
{
    const int t    = threadIdx.x;
    const int wave = t >> 6;
    const int lane = t & 63;

    if (blockIdx.x == 0 && t == 0) out[N_Q * CHN] = 1e-4f;  // loss seed

    if (blockIdx.x < M_ALL / 4) {
        const int row = blockIdx.x * 4 + wave;
        const float4 a = *(const float4*)(micro_all + (size_t)row * CHN + lane * 4);
        float4 w = *(const float4*)(fc_w + lane * 4);
        w.x -= INV_C; w.y -= INV_C; w.z -= INV_C; w.w -= INV_C;

        const float sx = a.x * w.x, sy = a.y * w.y, sz = a.z * w.z, sw = a.w * w.w;
        ushort4 pk;
        pk.x = bfbits(sx); pk.y = bfbits(sy); pk.z = bfbits(sz); pk.w = bfbits(sw);
        *(ushort4*)(aw + (size_t)row * CHN + lane * 4) = pk;

        float p = a.x * sx + a.y * sy + a.z * sz + a.w * sw;
        #pragma unroll
        for (int mask = 32; mask >= 1; mask >>= 1)
            p += __shfl_xor(p, mask, 64);
        if (lane == 0) bias[row] = p;
    } else {
        const int row = (blockIdx.x - M_ALL / 4) * 4 + wave;
        const float4 a = *(const float4*)(micro + (size_t)row * CHN + lane * 4);
        ushort4 pk;
        pk.x = bfbits(a.x); pk.y = bfbits(a.y); pk.z = bfbits(a.z); pk.w = bfbits(a.w);
        *(ushort4*)(bmic + (size_t)row * CHN + lane * 4) = pk;
    }
}

// ============ kernel 2: MFMA GEMM, zero LDS / zero barriers ============
// 512 blocks x 256 thr (2/CU). Fragments load straight from L2-resident bf16;
// wave->fragment map identical to the round-0 verified kernel.
#define BM 64
#define BN 32

__global__ __launch_bounds__(256) void gcn_gemm(
    const unsigned short* __restrict__ aw,
    const float* __restrict__ bias,
    const unsigned short* __restrict__ bmic,
    float* __restrict__ logits)
{
    const int t    = threadIdx.x;
    const int w    = t >> 6;
    const int l15  = t & 15;
    const int quad = (t >> 4) & 3;
    const int m0   = blockIdx.x * BM;
    const int n0   = blockIdx.y * BN;

    const int nt  = w & 1;   // n-tile (16 rows)
    const int mtp = w >> 1;  // m-half (32 rows)

    const unsigned short* brow  = bmic + (size_t)(n0 + nt * 16 + l15) * CHN;
    const unsigned short* arow0 = aw + (size_t)(m0 + mtp * 32 + l15) * CHN;
    const unsigned short* arow1 = arow0 + 16 * CHN;

    f32x4 acc0 = {0.f, 0.f, 0.f, 0.f};
    f32x4 acc1 = {0.f, 0.f, 0.f, 0.f};
    #pragma unroll
    for (int ks = 0; ks < 8; ++ks) {
        const int k0 = ks * 32 + quad * 8;
        const bf16x8 a  = *(const bf16x8*)(brow + k0);
        const bf16x8 b0 = *(const bf16x8*)(arow0 + k0);
        const bf16x8 b1 = *(const bf16x8*)(arow1 + k0);
        acc0 = __builtin_amdgcn_mfma_f32_16x16x32_bf16(a, b0, acc0, 0, 0, 0);
        acc1 = __builtin_amdgcn_mfma_f32_16x16x32_bf16(a, b1, acc1, 0, 0, 0);
    }

    const float bias0 = bias[m0 + mtp * 32 + l15];
    const float bias1 = bias[m0 + mtp * 32 + 16 + l15];
    #pragma unroll
    for (int reg = 0; reg < 4; ++reg) {
        const int n = n0 + nt * 16 + quad * 4 + reg;
        logits[(size_t)n * M_ALL + m0 + mtp * 32 + l15]      = bias0 - 2.f * acc0[reg];
        logits[(size_t)n * M_ALL + m0 + mtp * 32 + 16 + l15] = bias1 - 2.f * acc1[reg];
    }
}

// ============ kernel 3: packed-key top-k + exact refine + fused loss ============
#define BLOCK 256
#define WAVES (BLOCK / 64)
#define MPT   (M_ALL / BLOCK)
#define WTOP  8                   // per-wave exhaustive top-8 (packed keys)
#define NCAND (WAVES * WTOP)      // 32

__global__ __launch_bounds__(BLOCK) void gcn_topk(
    const float* __restrict__ logits,
    const float* __restrict__ micro,
    const float* __restrict__ label,
    const float* __restrict__ micro_all,
    const float* __restrict__ label_all,
    const float* __restrict__ fc_w,
    float* __restrict__ out)
{
    __shared__ unsigned s_keys[NCAND];
    __shared__ unsigned s_top[NREF];
    __shared__ float    s_ex[NREF];

    const int n    = blockIdx.x;
    const int t    = threadIdx.x;
    const int wave = t >> 6;
    const int lane = t & 63;

    // per-lane channel slice for the exact recompute (independent of logits)
    const float4 b4 = *(const float4*)(micro + (size_t)n * CHN + lane * 4);
    float4 w4 = *(const float4*)(fc_w + lane * 4);
    w4.x -= INV_C; w4.y -= INV_C; w4.z -= INV_C; w4.w -= INV_C;

    // contiguous per-thread slice: two float4 loads; m = t*8+j fits 11 bits
    unsigned k8[MPT];
    {
        const float4 v0 = *(const float4*)(logits + (size_t)n * M_ALL + t * 8);
        const float4 v1 = *(const float4*)(logits + (size_t)n * M_ALL + t * 8 + 4);
        const int mb = t * 8;
        k8[0] = key_of(v0.x, mb + 0);
        k8[1] = key_of(v0.y, mb + 1);
        k8[2] = key_of(v0.z, mb + 2);
        k8[3] = key_of(v0.w, mb + 3);
        k8[4] = key_of(v1.x, mb + 4);
        k8[5] = key_of(v1.y, mb + 5);
        k8[6] = key_of(v1.z, mb + 6);
        k8[7] = key_of(v1.w, mb + 7);
    }

    // ---- per-wave exhaustive top-8 via packed umax butterflies ----
    #pragma unroll
    for (int k = 0; k < WTOP; ++k) {
        unsigned best = k8[0];
        #pragma unroll
        for (int j = 1; j < MPT; ++j) best = (k8[j] > best) ? k8[j] : best;
        #pragma unroll
        for (int mask = 32; mask > 0; mask >>= 1) {
            const unsigned ov = __shfl_xor(best, mask, 64);
            best = (ov > best) ? ov : best;
        }
        if (lane == 0) s_keys[wave * WTOP + k] = best;
        #pragma unroll
        for (int j = 0; j < MPT; ++j)
            k8[j] = (k8[j] == best) ? 0u : k8[j];
    }
    __syncthreads();

    // ---- top-10 of the 32 candidates: 32-lane bitonic sort (descending) ----
    {
        unsigned v = s_keys[lane & 31];
        #pragma unroll
        for (int k = 2; k <= 32; k <<= 1) {
            #pragma unroll
            for (int j = k >> 1; j >= 1; j >>= 1) {
                const unsigned pv = __shfl_xor(v, j, 64);
                const unsigned mx = (v > pv) ? v : pv;
                const unsigned mn = (v > pv) ? pv : v;
                const bool up    = ((lane & k) == 0);
                const bool lower = ((lane & j) == 0);
                v = (up == lower) ? mx : mn;   // descending in "up" blocks
            }
        }
        if (wave == 0 && lane < NREF) s_top[lane] = v;  // lanes 0..9 descending
    }
    __syncthreads();

    // ---- exact fp32 recompute of the 10 candidates ----
    for (int c = wave; c < NREF; c += WAVES) {
        const int m = (int)(s_top[c] & 0x7FFu);
        const float4 a = *(const float4*)(micro_all + (size_t)m * CHN + lane * 4);
        const float dx = a.x - b4.x;
        const float dy = a.y - b4.y;
        const float dz = a.z - b4.z;
        const float dw = a.w - b4.w;
        float acc = dx * dx * w4.x + dy * dy * w4.y + dz * dz * w4.z + dw * dw * w4.w;
        #pragma unroll
        for (int mask = 32; mask >= 1; mask >>= 1)
            acc += __shfl_xor(acc, mask, 64);
        if (lane == 0) s_ex[c] = acc;
    }
    __syncthreads();

    // ---- exact top-6 of 10 (fp32, index-tracked, every thread identical) ----
    float top_val[TOPK];
    int   top_idx[TOPK];
    unsigned rtk = 0u;
    #pragma unroll
    for (int k = 0; k < TOPK; ++k) {
        float best = -INFINITY;
        int   bi   = 0;
        #pragma unroll
        for (int c = 0; c < NREF; ++c) {
            const bool avail = ((rtk >> c) & 1u) == 0u;
            const float cv = s_ex[c];
            if (avail && cv > best) { best = cv; bi = c; }
        }
        top_val[k] = best;
        top_idx[k] = (int)(s_top[bi] & 0x7FFu);
        rtk |= 1u << bi;
    }

    // ---- softmax over exact top-6 ----
    const float mx = top_val[0];
    float e[TOPK];
    float esum = 0.0f;
    #pragma unroll
    for (int k = 0; k < TOPK; ++k) { e[k] = __expf(top_val[k] - mx); esum += e[k]; }
    const float inv = 1.0f / esum;

    float outv = micro[(size_t)n * CHN + t];
    #pragma unroll
    for (int k = 0; k < TOPK; ++k)
        outv += (e[k] * inv) * micro_all[(size_t)top_idx[k] * CHN + t];
    out[n * CHN + t] = outv;

    // ---- fused loss: one device-scope atomic per block onto the 1e-4 seed ----
    if (t == 0) {
        const float lab = label[n];
        float l = 0.0f;
        #pragma unroll
        for (int k = 0; k < TOPK; ++k)
            l += (e[k] * inv) * fabsf(label_all[top_idx[k]] - lab);
        atomicAdd(out + N_Q * CHN, l * (1.0f / (float)N_Q));
    }
}

extern "C" void kernel_launch(void* const* d_in, const int* in_sizes, int n_in,
                              void* d_out, int out_size, void* d_ws, size_t ws_size,
                              hipStream_t stream) {
    const float* micro     = (const float*)d_in[0];
    const float* label     = (const float*)d_in[1];
    const float* micro_all = (const float*)d_in[2];
    const float* label_all = (const float*)d_in[3];
    const float* fc_w      = (const float*)d_in[4];
    float* out  = (float*)d_out;
    float* ws   = (float*)d_ws;
    unsigned short* aw     = (unsigned short*)(ws + WS_AW_F);
    float*          bias   = ws + WS_BIAS_F;
    unsigned short* bmic   = (unsigned short*)(ws + WS_BMIC_F);
    float*          logits = ws + WS_LOGIT_F;

    gcn_prep<<<M_ALL / 4 + N_Q / 4, 256, 0, stream>>>(
        micro_all, micro, fc_w, aw, bias, bmic, out);
    gcn_gemm<<<dim3(M_ALL / BM, N_Q / BN), 256, 0, stream>>>(
        aw, bias, bmic, logits);
    gcn_topk<<<N_Q, BLOCK, 0, stream>>>(logits, micro, label, micro_all,
                                        label_all, fc_w, out);
}